// Round 5
// baseline (1123.404 us; speedup 1.0000x reference)
//
#include <hip/hip_runtime.h>
#include <hip/hip_bf16.h>
#include <cstdint>
#include <cstddef>

// SingleheadTransformerDecoderLayer: L=S=2048, N=4, E=1024, FF=4096, fp32 I/O.
// Round 5: (1) split-K via fp32 atomicAdd for the residual-accumulate GEMMs
// (proj x2 splitk=2, MLP2 splitk=4) -- fixes 2-blocks/CU starvation seen in
// round-4 counters (occ 21%, MfmaUtil 20%, 480 TF); (2) all weight/bias casts
// fused into one launch.
//
// Workspace layout (161MB):
//   [0,32)    xf   : fp32 residual [8192,1024] (init = tgt, final = output)
//   [32,48)   hb   : bf16 LN out
//   [48,64)   vb   : bf16 V          } sb bf16 scores [n][l][s] = [32,64)
//   [64,80)   qb   : bf16 Q          }   (hb,vb dead by score-GEMM time)
//   [80,96)   kb   : bf16 K  (reused as attn-out ao after score GEMM)
//   [96,112)  vt   : bf16 V^T [n][e][s]
//   [48,112)  hid  : bf16 MLP hidden [8192,4096] (vb,qb,kb,vt dead)
//   [112,128) memb : bf16 copy of `memory`
//   [128,160) wts  : bf16 weights: saq,sak,sav,sao,caq,cak,cav,cao (1M each),
//                    w1 (4M), w2 (4M)
//   [160,161) bb   : bf16 biases: sa_b@0(3072) sa_ob@3072 ca_b@4096
//                    ca_ob@7168 b1@8192 b2@12288

using bf16_t = __bf16;
typedef __bf16 bf16x8 __attribute__((ext_vector_type(8)));
typedef __bf16 bf16x4 __attribute__((ext_vector_type(4)));
typedef float f32x4 __attribute__((ext_vector_type(4)));

// ---------------- async global->LDS, 16B/lane, wave-uniform LDS base --------
__device__ __forceinline__ void gll16(const void* g, void* lds) {
  __builtin_amdgcn_global_load_lds(
      (__attribute__((address_space(1))) void*)(g),
      (__attribute__((address_space(3))) void*)(lds), 16, 0, 0);
}

// ---------------- fp32 -> bf16 cast (8 elems/thread, n % 2048 == 0) ---------
__global__ __launch_bounds__(256) void f32_to_bf16_n(
    const float* __restrict__ in, bf16_t* __restrict__ out, int n) {
  const size_t i = ((size_t)blockIdx.x * 256 + threadIdx.x) * 8;
  if (i >= (size_t)n) return;
  f32x4 a = *(const f32x4*)(in + i);
  f32x4 b = *(const f32x4*)(in + i + 4);
  bf16x8 v;
#pragma unroll
  for (int j = 0; j < 4; ++j) { v[j] = (bf16_t)a[j]; v[4 + j] = (bf16_t)b[j]; }
  *(bf16x8*)(out + i) = v;
}

// ---------------- fused multi-segment fp32 -> bf16 cast ---------------------
// One block = one 1024-element chunk (256 thr x 4). Segment sizes % 1024 == 0.
struct CastSeg { const float* src; bf16_t* dst; int chunks; };
struct CastDesc { CastSeg s[16]; };
__global__ __launch_bounds__(256) void cast_multi(CastDesc d) {
  int blk = blockIdx.x, seg = 0, base = 0;
  while (blk - base >= d.s[seg].chunks) { base += d.s[seg].chunks; ++seg; }
  const size_t i = (size_t)(blk - base) * 1024 + threadIdx.x * 4;
  f32x4 a = *(const f32x4*)(d.s[seg].src + i);
  bf16x4 v;
#pragma unroll
  for (int j = 0; j < 4; ++j) v[j] = (bf16_t)a[j];
  *(bf16x4*)(d.s[seg].dst + i) = v;
}

// ---------------- LayerNorm over E=1024, one block per row ------------------
__global__ __launch_bounds__(256) void ln_kernel(
    const float* __restrict__ x, const float* __restrict__ g,
    const float* __restrict__ b, bf16_t* __restrict__ out) {
  const int row = blockIdx.x, tid = threadIdx.x;
  const float* xr = x + (size_t)row * 1024;
  float v0 = xr[tid], v1 = xr[tid + 256], v2 = xr[tid + 512], v3 = xr[tid + 768];
  float s = v0 + v1 + v2 + v3;
  float ss = v0 * v0 + v1 * v1 + v2 * v2 + v3 * v3;
#pragma unroll
  for (int off = 32; off > 0; off >>= 1) {
    s += __shfl_down(s, off, 64);
    ss += __shfl_down(ss, off, 64);
  }
  __shared__ float red[8];
  const int w = tid >> 6, lane = tid & 63;
  if (lane == 0) { red[w] = s; red[4 + w] = ss; }
  __syncthreads();
  s = red[0] + red[1] + red[2] + red[3];
  ss = red[4] + red[5] + red[6] + red[7];
  const float mean = s * (1.f / 1024.f);
  float var = ss * (1.f / 1024.f) - mean * mean;
  var = var < 0.f ? 0.f : var;
  const float inv = rsqrtf(var + 1e-5f);
  bf16_t* orow = out + (size_t)row * 1024;
  orow[tid]       = (bf16_t)((v0 - mean) * inv * g[tid]       + b[tid]);
  orow[tid + 256] = (bf16_t)((v1 - mean) * inv * g[tid + 256] + b[tid + 256]);
  orow[tid + 512] = (bf16_t)((v2 - mean) * inv * g[tid + 512] + b[tid + 512]);
  orow[tid + 768] = (bf16_t)((v3 - mean) * inv * g[tid + 768] + b[tid + 768]);
}

// ---------------- softmax over S=2048, bf16 in-place, optional causal -------
template <int CAUSAL>
__global__ __launch_bounds__(256) void softmax_kernel(bf16_t* __restrict__ sc) {
  const int row = blockIdx.x, tid = threadIdx.x;
  const int l = row & 2047;
  bf16_t* sr = sc + (size_t)row * 2048;
  float v[8];
  float mx = -3.4e38f;
#pragma unroll
  for (int i = 0; i < 8; ++i) {
    const int j = tid + i * 256;
    v[i] = (CAUSAL && j > l) ? -3.4e38f : (float)sr[j];
    mx = fmaxf(mx, v[i]);
  }
#pragma unroll
  for (int off = 32; off > 0; off >>= 1) mx = fmaxf(mx, __shfl_down(mx, off, 64));
  __shared__ float red[8];
  const int w = tid >> 6, lane = tid & 63;
  if (lane == 0) red[w] = mx;
  __syncthreads();
  mx = fmaxf(fmaxf(red[0], red[1]), fmaxf(red[2], red[3]));
  float sum = 0.f;
#pragma unroll
  for (int i = 0; i < 8; ++i) { v[i] = __expf(v[i] - mx); sum += v[i]; }
#pragma unroll
  for (int off = 32; off > 0; off >>= 1) sum += __shfl_down(sum, off, 64);
  if (lane == 0) red[4 + w] = sum;
  __syncthreads();
  sum = red[4] + red[5] + red[6] + red[7];
  const float r = 1.f / sum;
#pragma unroll
  for (int i = 0; i < 8; ++i) sr[tid + i * 256] = (bf16_t)(v[i] * r);
}

// ---------------- V transpose: [s*4+n, e] -> vt[n][e][s] --------------------
__global__ __launch_bounds__(256) void transpose_v(const bf16_t* __restrict__ v,
                                                   bf16_t* __restrict__ vt) {
  __shared__ bf16_t tile[64][72];
  const int n = blockIdx.z;
  const int s0 = blockIdx.x * 64, e0 = blockIdx.y * 64;
  const int tid = threadIdx.x;
#pragma unroll
  for (int j = 0; j < 2; ++j) {
    int flat = j * 256 + tid;
    int r = flat >> 3, c8 = (flat & 7) * 8;
    bf16x8 val = *(const bf16x8*)(v + ((size_t)(s0 + r) * 4 + n) * 1024 + e0 + c8);
#pragma unroll
    for (int i = 0; i < 8; ++i) tile[r][c8 + i] = val[i];
  }
  __syncthreads();
#pragma unroll
  for (int j = 0; j < 2; ++j) {
    int flat = j * 256 + tid;
    int er = flat >> 3, s8 = (flat & 7) * 8;
    bf16x8 val;
#pragma unroll
    for (int i = 0; i < 8; ++i) val[i] = tile[s8 + i][er];
    *(bf16x8*)(vt + ((size_t)n * 1024 + e0 + er) * 2048 + s0 + s8) = val;
  }
}

// ---------------- generic C = A @ W^T GEMM (m97 structure) ------------------
// All operands bf16. 128x128 tile, BK=32, 4 waves x (4x4) 16x16x32 MFMA,
// global_load_lds width-16 staging.
// EPI: 0 = bf16 store (acc+bias)*scale; 1 = bf16 store acc;
//      2 = fp32 residual accumulate acc+bias (atomicAdd when SPLITK>1);
//      3 = QuickGELU -> bf16.
// MODE: 0 = plain (zb = batch, strides sA/sW/sC);
//       1 = causal score (skip tiles col0 > row0);
//       2 = causal PV (K capped at row0+128);
//       3 = fused QKV (zb selects A/Aalt, W0..2, C0..2, bias += zb*1024,
//           scale applies to zb==0 only).
// SPLITK: blockIdx.z = zb*SPLITK + kc; block computes K-chunk kc.
template <int EPI, int MODE, int SPLITK>
__global__ __launch_bounds__(256) void gemm_bt(
    const bf16_t* __restrict__ A, const bf16_t* __restrict__ Aalt,
    long lda, long sA,
    const bf16_t* __restrict__ W0, const bf16_t* __restrict__ W1,
    const bf16_t* __restrict__ W2, long ldw, long sW,
    void* __restrict__ C0, void* __restrict__ C1, void* __restrict__ C2,
    long ldc, long sC,
    const bf16_t* __restrict__ bias, float scale, int K) {
  const size_t row0 = (size_t)blockIdx.y * 128;
  const size_t col0 = (size_t)blockIdx.x * 128;
  if (MODE == 1 && col0 > row0) return;  // fully-masked causal tile
  const int z = blockIdx.z;
  const int zb = (SPLITK > 1) ? z / SPLITK : z;
  const int kc = (SPLITK > 1) ? z % SPLITK : 0;

  const bf16_t* Ap = (MODE == 3) ? (zb == 0 ? A : Aalt) : A + (size_t)zb * sA;
  const bf16_t* Wp = (MODE == 3) ? (zb == 0 ? W0 : (zb == 1 ? W1 : W2))
                                 : W0 + (size_t)zb * sW;
  void* Cp = (MODE == 3) ? (zb == 0 ? C0 : (zb == 1 ? C1 : C2)) : C0;
  const size_t zoffC = (MODE == 3) ? 0 : (size_t)zb * sC;
  const bf16_t* biasp = bias ? bias + (MODE == 3 ? zb * 1024 : 0) : nullptr;
  const float scl = (MODE == 3 && zb != 0) ? 1.f : scale;

  const int Kchunk = (SPLITK > 1) ? K / SPLITK : K;
  const int kbeg = kc * Kchunk;
  int kend = kbeg + Kchunk;
  if (MODE == 2) kend = min(kend, (int)row0 + 128);

  __shared__ __align__(16) bf16_t As[128 * 32];
  __shared__ __align__(16) bf16_t Bs[128 * 32];
  const int tid = threadIdx.x;
  const int wv = tid >> 6, lane = tid & 63;
  const int quad = lane >> 4, l15 = lane & 15;
  const int wr = wv >> 1, wc = wv & 1;

  // staging: chunk ci = (wv*2+j)*64 + lane -> tile row ci>>2, cols (ci&3)*8;
  // LDS dest = wave-uniform base + lane*16B (HW behavior of global_load_lds).
  const int ci0 = wv * 128 + lane, ci1 = ci0 + 64;
  const int ra0 = ci0 >> 2, ca0 = (ci0 & 3) * 8;
  const int ra1 = ci1 >> 2, ca1 = (ci1 & 3) * 8;
  bf16_t* ldsA0 = As + (size_t)(wv * 2 + 0) * 512;
  bf16_t* ldsA1 = As + (size_t)(wv * 2 + 1) * 512;
  bf16_t* ldsB0 = Bs + (size_t)(wv * 2 + 0) * 512;
  bf16_t* ldsB1 = Bs + (size_t)(wv * 2 + 1) * 512;
  const bf16_t* pA0 = Ap + (row0 + ra0) * lda + ca0;
  const bf16_t* pA1 = Ap + (row0 + ra1) * lda + ca1;
  const bf16_t* pW0 = Wp + (col0 + ra0) * ldw + ca0;
  const bf16_t* pW1 = Wp + (col0 + ra1) * ldw + ca1;

  f32x4 acc[4][4];
#pragma unroll
  for (int mi = 0; mi < 4; ++mi)
#pragma unroll
    for (int ni = 0; ni < 4; ++ni) acc[mi][ni] = (f32x4)0.f;

  for (int k0 = kbeg; k0 < kend; k0 += 32) {
    gll16(pA0 + k0, ldsA0);
    gll16(pA1 + k0, ldsA1);
    gll16(pW0 + k0, ldsB0);
    gll16(pW1 + k0, ldsB1);
    __syncthreads();  // drains vmcnt(0): LDS staging complete
    bf16x8 af[4], bfv[4];
#pragma unroll
    for (int mi = 0; mi < 4; ++mi)
      af[mi] = *(const bf16x8*)(As + (wr * 64 + mi * 16 + l15) * 32 + quad * 8);
#pragma unroll
    for (int ni = 0; ni < 4; ++ni)
      bfv[ni] = *(const bf16x8*)(Bs + (wc * 64 + ni * 16 + l15) * 32 + quad * 8);
#pragma unroll
    for (int mi = 0; mi < 4; ++mi)
#pragma unroll
      for (int ni = 0; ni < 4; ++ni)
        acc[mi][ni] = __builtin_amdgcn_mfma_f32_16x16x32_bf16(
            af[mi], bfv[ni], acc[mi][ni], 0, 0, 0);
    __syncthreads();  // LDS reuse next iteration
  }

  // epilogue: C/D layout col=lane&15, row=quad*4+r (verified m89/m91)
  float* Cf = (float*)Cp;
  bf16_t* Cb = (bf16_t*)Cp;
#pragma unroll
  for (int mi = 0; mi < 4; ++mi) {
    const size_t gr = row0 + wr * 64 + mi * 16 + quad * 4;
#pragma unroll
    for (int ni = 0; ni < 4; ++ni) {
      const size_t gc = col0 + wc * 64 + ni * 16 + l15;
      float bv = 0.f;
      if (EPI == 0 || EPI == 2 || EPI == 3) bv = biasp ? (float)biasp[gc] : 0.f;
      if (SPLITK > 1 && kc != 0) bv = 0.f;
#pragma unroll
      for (int r = 0; r < 4; ++r) {
        float v = acc[mi][ni][r];
        const size_t idx = zoffC + (gr + r) * ldc + gc;
        if (EPI == 0) {
          Cb[idx] = (bf16_t)((v + bv) * scl);
        } else if (EPI == 1) {
          Cb[idx] = (bf16_t)v;
        } else if (EPI == 2) {
          if (SPLITK > 1) atomicAdd(&Cf[idx], v + bv);
          else Cf[idx] += v + bv;
        } else {
          float t = v + bv;
          Cb[idx] = (bf16_t)(t * (1.f / (1.f + __expf(-1.702f * t))));
        }
      }
    }
  }
}

// ---------------- host-side launch helper -----------------------------------
template <int EPI, int MODE, int SPLITK = 1>
static void launch_gemm(hipStream_t stream, int M, int N, int Z,
                        const void* A, const void* Aalt, long lda, long sA,
                        const void* W0, const void* W1, const void* W2,
                        long ldw, long sW,
                        void* C0, void* C1, void* C2, long ldc, long sC,
                        const void* bias, float scale, int K) {
  dim3 grid(N / 128, M / 128, Z * SPLITK);
  gemm_bt<EPI, MODE, SPLITK><<<grid, dim3(256), 0, stream>>>(
      (const bf16_t*)A, (const bf16_t*)Aalt, lda, sA,
      (const bf16_t*)W0, (const bf16_t*)W1, (const bf16_t*)W2, ldw, sW,
      C0, C1, C2, ldc, sC, (const bf16_t*)bias, scale, K);
}

extern "C" void kernel_launch(void* const* d_in, const int* in_sizes, int n_in,
                              void* d_out, int out_size, void* d_ws, size_t ws_size,
                              hipStream_t stream) {
  (void)in_sizes; (void)n_in; (void)out_size; (void)ws_size;
  const float* tgt  = (const float*)d_in[0];
  const float* mem  = (const float*)d_in[1];
  // d_in[2] (mask) unused: causality applied structurally.
  const float* sa_qw = (const float*)d_in[3];
  const float* sa_kw = (const float*)d_in[4];
  const float* sa_vw = (const float*)d_in[5];
  const float* sa_b  = (const float*)d_in[6];
  const float* sa_ow = (const float*)d_in[7];
  const float* sa_ob = (const float*)d_in[8];
  const float* ca_qw = (const float*)d_in[9];
  const float* ca_kw = (const float*)d_in[10];
  const float* ca_vw = (const float*)d_in[11];
  const float* ca_b  = (const float*)d_in[12];
  const float* ca_ow = (const float*)d_in[13];
  const float* ca_ob = (const float*)d_in[14];
  const float* ln1g = (const float*)d_in[15];
  const float* ln1b = (const float*)d_in[16];
  const float* ln2g = (const float*)d_in[17];
  const float* ln2b = (const float*)d_in[18];
  const float* ln3g = (const float*)d_in[19];
  const float* ln3b = (const float*)d_in[20];
  const float* w1 = (const float*)d_in[21];
  const float* b1 = (const float*)d_in[22];
  const float* w2 = (const float*)d_in[23];
  const float* b2 = (const float*)d_in[24];

  char* ws = (char*)d_ws;
  const size_t MB = 1048576;
  float*  xf   = (float*)(ws);             // [0,32)   fp32 residual
  bf16_t* hb   = (bf16_t*)(ws + 32 * MB);  // [32,48)  LN out
  bf16_t* vb   = (bf16_t*)(ws + 48 * MB);  // [48,64)  V
  bf16_t* qb   = (bf16_t*)(ws + 64 * MB);  // [64,80)  Q
  bf16_t* kb   = (bf16_t*)(ws + 80 * MB);  // [80,96)  K
  bf16_t* vt   = (bf16_t*)(ws + 96 * MB);  // [96,112) V^T [n][e][s]
  bf16_t* sb   = (bf16_t*)(ws + 32 * MB);  // [32,64)  scores/probs
  bf16_t* ao   = kb;                       // [80,96)  attn out (kb dead)
  bf16_t* hid  = (bf16_t*)(ws + 48 * MB);  // [48,112) MLP hidden
  bf16_t* memb = (bf16_t*)(ws + 112 * MB); // [112,128) bf16 memory
  bf16_t* wt   = (bf16_t*)(ws + 128 * MB); // [128,160) bf16 weights
  bf16_t* bb   = (bf16_t*)(ws + 160 * MB); // biases

  const size_t M1 = 1048576;  // elems per E*E weight
  bf16_t* saq = wt,          *sak = wt + M1,     *sav = wt + 2 * M1;
  bf16_t* sao = wt + 3 * M1, *caq = wt + 4 * M1, *cak = wt + 5 * M1;
  bf16_t* cav = wt + 6 * M1, *cao = wt + 7 * M1;
  bf16_t* w1b = wt + 8 * M1;   // 4M elems
  bf16_t* w2b = wt + 12 * M1;  // 4M elems

  const float qscale = 0.03125f;  // 1024^-0.5

  // ---- fused weight/bias conversions (one launch) ----
  CastDesc cd;
  const int C1K = 1024;  // elems per chunk
  auto seg = [&](int i, const float* s, bf16_t* d, int elems) {
    cd.s[i] = CastSeg{s, d, elems / C1K};
  };
  seg(0, sa_qw, saq, 1 << 20);  seg(1, sa_kw, sak, 1 << 20);
  seg(2, sa_vw, sav, 1 << 20);  seg(3, sa_ow, sao, 1 << 20);
  seg(4, ca_qw, caq, 1 << 20);  seg(5, ca_kw, cak, 1 << 20);
  seg(6, ca_vw, cav, 1 << 20);  seg(7, ca_ow, cao, 1 << 20);
  seg(8, w1, w1b, 1 << 22);     seg(9, w2, w2b, 1 << 22);
  seg(10, sa_b, bb, 3072);      seg(11, sa_ob, bb + 3072, 1024);
  seg(12, ca_b, bb + 4096, 3072); seg(13, ca_ob, bb + 7168, 1024);
  seg(14, b1, bb + 8192, 4096); seg(15, b2, bb + 12288, 1024);
  int total_chunks = 0;
  for (int i = 0; i < 16; ++i) total_chunks += cd.s[i].chunks;
  cast_multi<<<total_chunks, 256, 0, stream>>>(cd);
  f32_to_bf16_n<<<4096, 256, 0, stream>>>(mem, memb, 1 << 23);
  hipMemcpyAsync(xf, tgt, 32 * MB, hipMemcpyDeviceToDevice, stream);

  // ================= self-attention (causal) =================
  ln_kernel<<<8192, 256, 0, stream>>>(xf, ln1g, ln1b, hb);
  launch_gemm<0, 3>(stream, 8192, 1024, 3, hb, hb, 1024, 0,
                    saq, sak, sav, 1024, 0, qb, kb, vb, 1024, 0,
                    bb, qscale, 1024);
  transpose_v<<<dim3(32, 16, 4), 256, 0, stream>>>(vb, vt);
  launch_gemm<1, 1>(stream, 2048, 2048, 4, qb, nullptr, 4096, 1024,
                    kb, nullptr, nullptr, 4096, 1024,
                    sb, nullptr, nullptr, 2048, 4194304, nullptr, 1.f, 1024);
  softmax_kernel<1><<<8192, 256, 0, stream>>>(sb);
  launch_gemm<0, 2>(stream, 2048, 1024, 4, sb, nullptr, 2048, 4194304,
                    vt, nullptr, nullptr, 2048, 2097152,
                    ao, nullptr, nullptr, 4096, 1024, nullptr, 1.f, 2048);
  launch_gemm<2, 0, 2>(stream, 8192, 1024, 1, ao, nullptr, 1024, 0,
                       sao, nullptr, nullptr, 1024, 0,
                       xf, nullptr, nullptr, 1024, 0, bb + 3072, 1.f, 1024);

  // ================= cross-attention (no mask) =================
  ln_kernel<<<8192, 256, 0, stream>>>(xf, ln2g, ln2b, hb);
  launch_gemm<0, 3>(stream, 8192, 1024, 3, hb, memb, 1024, 0,
                    caq, cak, cav, 1024, 0, qb, kb, vb, 1024, 0,
                    bb + 4096, qscale, 1024);
  transpose_v<<<dim3(32, 16, 4), 256, 0, stream>>>(vb, vt);
  launch_gemm<1, 0>(stream, 2048, 2048, 4, qb, nullptr, 4096, 1024,
                    kb, nullptr, nullptr, 4096, 1024,
                    sb, nullptr, nullptr, 2048, 4194304, nullptr, 1.f, 1024);
  softmax_kernel<0><<<8192, 256, 0, stream>>>(sb);
  launch_gemm<0, 0>(stream, 2048, 1024, 4, sb, nullptr, 2048, 4194304,
                    vt, nullptr, nullptr, 2048, 2097152,
                    ao, nullptr, nullptr, 4096, 1024, nullptr, 1.f, 2048);
  launch_gemm<2, 0, 2>(stream, 8192, 1024, 1, ao, nullptr, 1024, 0,
                       cao, nullptr, nullptr, 1024, 0,
                       xf, nullptr, nullptr, 1024, 0, bb + 7168, 1.f, 1024);

  // ================= MLP (QuickGELU) =================
  ln_kernel<<<8192, 256, 0, stream>>>(xf, ln3g, ln3b, hb);
  launch_gemm<3, 0>(stream, 8192, 4096, 1, hb, nullptr, 1024, 0,
                    w1b, nullptr, nullptr, 1024, 0,
                    hid, nullptr, nullptr, 4096, 0, bb + 8192, 1.f, 1024);
  launch_gemm<2, 0, 4>(stream, 8192, 1024, 1, hid, nullptr, 4096, 0,
                       w2b, nullptr, nullptr, 4096, 0,
                       xf, nullptr, nullptr, 1024, 0, bb + 12288, 1.f, 4096);

  hipMemcpyAsync(d_out, xf, 32 * MB, hipMemcpyDeviceToDevice, stream);
}

// Round 6
// 899.617 us; speedup vs baseline: 1.2488x; 1.2488x over previous
//
#include <hip/hip_runtime.h>
#include <hip/hip_bf16.h>
#include <cstdint>
#include <cstddef>

// SingleheadTransformerDecoderLayer: L=S=2048, N=4, E=1024, FF=4096, fp32 I/O.
// Round 6: (1) REVERT split-K atomics (regressed: 4x WRITE traffic);
// (2) double-buffered LDS GEMM: one barrier/K-iter, prefetch issued after the
// barrier so global_load_lds overlaps MFMA (targets the 52% stall at
// 2-blocks/CU grids); (3) residual reads fused into EPI=2 epilogue (no
// memcpys: proj reads tgt/xf, MLP2 writes d_out directly).
//
// Workspace layout (161MB):
//   [0,32)    xf   : fp32 residual [8192,1024]
//   [32,48)   hb   : bf16 LN out
//   [48,64)   vb   : bf16 V          } sb bf16 scores [n][l][s] = [32,64)
//   [64,80)   qb   : bf16 Q          }   (hb,vb dead by score-GEMM time)
//   [80,96)   kb   : bf16 K  (reused as attn-out ao after score GEMM)
//   [96,112)  vt   : bf16 V^T [n][e][s]
//   [48,112)  hid  : bf16 MLP hidden [8192,4096] (vb,qb,kb,vt dead)
//   [112,128) memb : bf16 copy of `memory`
//   [128,160) wts  : bf16 weights: saq,sak,sav,sao,caq,cak,cav,cao (1M each),
//                    w1 (4M), w2 (4M)
//   [160,161) bb   : bf16 biases: sa_b@0(3072) sa_ob@3072 ca_b@4096
//                    ca_ob@7168 b1@8192 b2@12288

using bf16_t = __bf16;
typedef __bf16 bf16x8 __attribute__((ext_vector_type(8)));
typedef __bf16 bf16x4 __attribute__((ext_vector_type(4)));
typedef float f32x4 __attribute__((ext_vector_type(4)));

// ---------------- async global->LDS, 16B/lane, wave-uniform LDS base --------
__device__ __forceinline__ void gll16(const void* g, void* lds) {
  __builtin_amdgcn_global_load_lds(
      (__attribute__((address_space(1))) void*)(g),
      (__attribute__((address_space(3))) void*)(lds), 16, 0, 0);
}

// ---------------- fp32 -> bf16 cast (8 elems/thread) ------------------------
__global__ __launch_bounds__(256) void f32_to_bf16_n(
    const float* __restrict__ in, bf16_t* __restrict__ out, int n) {
  const size_t i = ((size_t)blockIdx.x * 256 + threadIdx.x) * 8;
  if (i >= (size_t)n) return;
  f32x4 a = *(const f32x4*)(in + i);
  f32x4 b = *(const f32x4*)(in + i + 4);
  bf16x8 v;
#pragma unroll
  for (int j = 0; j < 4; ++j) { v[j] = (bf16_t)a[j]; v[4 + j] = (bf16_t)b[j]; }
  *(bf16x8*)(out + i) = v;
}

// ---------------- fused multi-segment fp32 -> bf16 cast ---------------------
struct CastSeg { const float* src; bf16_t* dst; int chunks; };
struct CastDesc { CastSeg s[16]; };
__global__ __launch_bounds__(256) void cast_multi(CastDesc d) {
  int blk = blockIdx.x, seg = 0, base = 0;
  while (blk - base >= d.s[seg].chunks) { base += d.s[seg].chunks; ++seg; }
  const size_t i = (size_t)(blk - base) * 1024 + threadIdx.x * 4;
  f32x4 a = *(const f32x4*)(d.s[seg].src + i);
  bf16x4 v;
#pragma unroll
  for (int j = 0; j < 4; ++j) v[j] = (bf16_t)a[j];
  *(bf16x4*)(d.s[seg].dst + i) = v;
}

// ---------------- LayerNorm over E=1024, one block per row ------------------
__global__ __launch_bounds__(256) void ln_kernel(
    const float* __restrict__ x, const float* __restrict__ g,
    const float* __restrict__ b, bf16_t* __restrict__ out) {
  const int row = blockIdx.x, tid = threadIdx.x;
  const float* xr = x + (size_t)row * 1024;
  float v0 = xr[tid], v1 = xr[tid + 256], v2 = xr[tid + 512], v3 = xr[tid + 768];
  float s = v0 + v1 + v2 + v3;
  float ss = v0 * v0 + v1 * v1 + v2 * v2 + v3 * v3;
#pragma unroll
  for (int off = 32; off > 0; off >>= 1) {
    s += __shfl_down(s, off, 64);
    ss += __shfl_down(ss, off, 64);
  }
  __shared__ float red[8];
  const int w = tid >> 6, lane = tid & 63;
  if (lane == 0) { red[w] = s; red[4 + w] = ss; }
  __syncthreads();
  s = red[0] + red[1] + red[2] + red[3];
  ss = red[4] + red[5] + red[6] + red[7];
  const float mean = s * (1.f / 1024.f);
  float var = ss * (1.f / 1024.f) - mean * mean;
  var = var < 0.f ? 0.f : var;
  const float inv = rsqrtf(var + 1e-5f);
  bf16_t* orow = out + (size_t)row * 1024;
  orow[tid]       = (bf16_t)((v0 - mean) * inv * g[tid]       + b[tid]);
  orow[tid + 256] = (bf16_t)((v1 - mean) * inv * g[tid + 256] + b[tid + 256]);
  orow[tid + 512] = (bf16_t)((v2 - mean) * inv * g[tid + 512] + b[tid + 512]);
  orow[tid + 768] = (bf16_t)((v3 - mean) * inv * g[tid + 768] + b[tid + 768]);
}

// ---------------- softmax over S=2048, bf16 in-place, optional causal -------
template <int CAUSAL>
__global__ __launch_bounds__(256) void softmax_kernel(bf16_t* __restrict__ sc) {
  const int row = blockIdx.x, tid = threadIdx.x;
  const int l = row & 2047;
  bf16_t* sr = sc + (size_t)row * 2048;
  float v[8];
  float mx = -3.4e38f;
#pragma unroll
  for (int i = 0; i < 8; ++i) {
    const int j = tid + i * 256;
    v[i] = (CAUSAL && j > l) ? -3.4e38f : (float)sr[j];
    mx = fmaxf(mx, v[i]);
  }
#pragma unroll
  for (int off = 32; off > 0; off >>= 1) mx = fmaxf(mx, __shfl_down(mx, off, 64));
  __shared__ float red[8];
  const int w = tid >> 6, lane = tid & 63;
  if (lane == 0) red[w] = mx;
  __syncthreads();
  mx = fmaxf(fmaxf(red[0], red[1]), fmaxf(red[2], red[3]));
  float sum = 0.f;
#pragma unroll
  for (int i = 0; i < 8; ++i) { v[i] = __expf(v[i] - mx); sum += v[i]; }
#pragma unroll
  for (int off = 32; off > 0; off >>= 1) sum += __shfl_down(sum, off, 64);
  if (lane == 0) red[4 + w] = sum;
  __syncthreads();
  sum = red[4] + red[5] + red[6] + red[7];
  const float r = 1.f / sum;
#pragma unroll
  for (int i = 0; i < 8; ++i) sr[tid + i * 256] = (bf16_t)(v[i] * r);
}

// ---------------- V transpose: [s*4+n, e] -> vt[n][e][s] --------------------
__global__ __launch_bounds__(256) void transpose_v(const bf16_t* __restrict__ v,
                                                   bf16_t* __restrict__ vt) {
  __shared__ bf16_t tile[64][72];
  const int n = blockIdx.z;
  const int s0 = blockIdx.x * 64, e0 = blockIdx.y * 64;
  const int tid = threadIdx.x;
#pragma unroll
  for (int j = 0; j < 2; ++j) {
    int flat = j * 256 + tid;
    int r = flat >> 3, c8 = (flat & 7) * 8;
    bf16x8 val = *(const bf16x8*)(v + ((size_t)(s0 + r) * 4 + n) * 1024 + e0 + c8);
#pragma unroll
    for (int i = 0; i < 8; ++i) tile[r][c8 + i] = val[i];
  }
  __syncthreads();
#pragma unroll
  for (int j = 0; j < 2; ++j) {
    int flat = j * 256 + tid;
    int er = flat >> 3, s8 = (flat & 7) * 8;
    bf16x8 val;
#pragma unroll
    for (int i = 0; i < 8; ++i) val[i] = tile[s8 + i][er];
    *(bf16x8*)(vt + ((size_t)n * 1024 + e0 + er) * 2048 + s0 + s8) = val;
  }
}

// ---------------- generic C = A @ W^T GEMM, double-buffered LDS -------------
// All operands bf16. 128x128 tile, BK=32, 4 waves x (4x4) 16x16x32 MFMA,
// global_load_lds width-16 staging, 2-deep LDS pipeline (one barrier/iter;
// prefetch of tile k+1 issued after the barrier, in flight during MFMA k).
// EPI: 0 = bf16 store (acc+bias)*scale; 1 = bf16 store acc;
//      2 = fp32 store res[idx]+acc+bias; 3 = QuickGELU -> bf16.
// MODE: 0 = plain (z = batch, strides sA/sW/sC);
//       1 = causal score (skip tiles col0 > row0);
//       2 = causal PV (K capped at row0+128);
//       3 = fused QKV (z selects A/Aalt, W0..2, C0..2, bias += z*1024,
//           scale applies to z==0 only).
template <int EPI, int MODE>
__global__ __launch_bounds__(256) void gemm_bt(
    const bf16_t* __restrict__ A, const bf16_t* __restrict__ Aalt,
    long lda, long sA,
    const bf16_t* __restrict__ W0, const bf16_t* __restrict__ W1,
    const bf16_t* __restrict__ W2, long ldw, long sW,
    void* __restrict__ C0, void* __restrict__ C1, void* __restrict__ C2,
    long ldc, long sC,
    const bf16_t* __restrict__ bias, const float* __restrict__ res,
    float scale, int K) {
  const size_t row0 = (size_t)blockIdx.y * 128;
  const size_t col0 = (size_t)blockIdx.x * 128;
  if (MODE == 1 && col0 > row0) return;  // fully-masked causal tile
  const int z = blockIdx.z;

  const bf16_t* Ap = (MODE == 3) ? (z == 0 ? A : Aalt) : A + (size_t)z * sA;
  const bf16_t* Wp = (MODE == 3) ? (z == 0 ? W0 : (z == 1 ? W1 : W2))
                                 : W0 + (size_t)z * sW;
  void* Cp = (MODE == 3) ? (z == 0 ? C0 : (z == 1 ? C1 : C2)) : C0;
  const size_t zoffC = (MODE == 3) ? 0 : (size_t)z * sC;
  const bf16_t* biasp = bias ? bias + (MODE == 3 ? z * 1024 : 0) : nullptr;
  const float scl = (MODE == 3 && z != 0) ? 1.f : scale;
  const int kend = (MODE == 2) ? min(K, (int)row0 + 128) : K;

  __shared__ __align__(16) bf16_t As[2][128 * 32];
  __shared__ __align__(16) bf16_t Bs[2][128 * 32];
  const int tid = threadIdx.x;
  const int wv = tid >> 6, lane = tid & 63;
  const int quad = lane >> 4, l15 = lane & 15;
  const int wr = wv >> 1, wc = wv & 1;

  // staging: chunk ci = wv*128 + j*64 + lane -> tile row ci>>2, cols (ci&3)*8;
  // LDS dest = wave-uniform base + lane*16B (HW behavior of global_load_lds).
  const int ci0 = wv * 128 + lane, ci1 = ci0 + 64;
  const int ra0 = ci0 >> 2, ca0 = (ci0 & 3) * 8;
  const int ra1 = ci1 >> 2, ca1 = (ci1 & 3) * 8;
  const bf16_t* pA0 = Ap + (row0 + ra0) * lda + ca0;
  const bf16_t* pA1 = Ap + (row0 + ra1) * lda + ca1;
  const bf16_t* pW0 = Wp + (col0 + ra0) * ldw + ca0;
  const bf16_t* pW1 = Wp + (col0 + ra1) * ldw + ca1;
  const int ldsoff0 = wv * 1024, ldsoff1 = wv * 1024 + 512;

  f32x4 acc[4][4];
#pragma unroll
  for (int mi = 0; mi < 4; ++mi)
#pragma unroll
    for (int ni = 0; ni < 4; ++ni) acc[mi][ni] = (f32x4)0.f;

  // prologue: stage k=0 into parity 0
  gll16(pA0, As[0] + ldsoff0);
  gll16(pA1, As[0] + ldsoff1);
  gll16(pW0, Bs[0] + ldsoff0);
  gll16(pW1, Bs[0] + ldsoff1);

  int p = 0;
  for (int k0 = 0; k0 < kend; k0 += 32, p ^= 1) {
    __syncthreads();  // drains vmcnt(0): parity-p staging complete; also
                      // guarantees prior iter's ds_reads done before overwrite
    const int kn = k0 + 32;
    if (kn < kend) {  // prefetch parity p^1 — in flight during MFMA below
      gll16(pA0 + kn, As[p ^ 1] + ldsoff0);
      gll16(pA1 + kn, As[p ^ 1] + ldsoff1);
      gll16(pW0 + kn, Bs[p ^ 1] + ldsoff0);
      gll16(pW1 + kn, Bs[p ^ 1] + ldsoff1);
    }
    bf16x8 af[4], bfv[4];
#pragma unroll
    for (int mi = 0; mi < 4; ++mi)
      af[mi] = *(const bf16x8*)(As[p] + (wr * 64 + mi * 16 + l15) * 32 + quad * 8);
#pragma unroll
    for (int ni = 0; ni < 4; ++ni)
      bfv[ni] = *(const bf16x8*)(Bs[p] + (wc * 64 + ni * 16 + l15) * 32 + quad * 8);
#pragma unroll
    for (int mi = 0; mi < 4; ++mi)
#pragma unroll
      for (int ni = 0; ni < 4; ++ni)
        acc[mi][ni] = __builtin_amdgcn_mfma_f32_16x16x32_bf16(
            af[mi], bfv[ni], acc[mi][ni], 0, 0, 0);
  }

  // epilogue: C/D layout col=lane&15, row=quad*4+r (verified m89/m91)
  float* Cf = (float*)Cp;
  bf16_t* Cb = (bf16_t*)Cp;
#pragma unroll
  for (int mi = 0; mi < 4; ++mi) {
    const size_t gr = row0 + wr * 64 + mi * 16 + quad * 4;
#pragma unroll
    for (int ni = 0; ni < 4; ++ni) {
      const size_t gc = col0 + wc * 64 + ni * 16 + l15;
      float bv = 0.f;
      if (EPI == 0 || EPI == 2 || EPI == 3) bv = biasp ? (float)biasp[gc] : 0.f;
#pragma unroll
      for (int r = 0; r < 4; ++r) {
        float v = acc[mi][ni][r];
        const size_t idx = zoffC + (gr + r) * ldc + gc;
        if (EPI == 0) {
          Cb[idx] = (bf16_t)((v + bv) * scl);
        } else if (EPI == 1) {
          Cb[idx] = (bf16_t)v;
        } else if (EPI == 2) {
          Cf[idx] = res[idx] + v + bv;
        } else {
          float t = v + bv;
          Cb[idx] = (bf16_t)(t * (1.f / (1.f + __expf(-1.702f * t))));
        }
      }
    }
  }
}

// ---------------- host-side launch helper -----------------------------------
template <int EPI, int MODE>
static void launch_gemm(hipStream_t stream, int M, int N, int Z,
                        const void* A, const void* Aalt, long lda, long sA,
                        const void* W0, const void* W1, const void* W2,
                        long ldw, long sW,
                        void* C0, void* C1, void* C2, long ldc, long sC,
                        const void* bias, const float* res, float scale, int K) {
  dim3 grid(N / 128, M / 128, Z);
  gemm_bt<EPI, MODE><<<grid, dim3(256), 0, stream>>>(
      (const bf16_t*)A, (const bf16_t*)Aalt, lda, sA,
      (const bf16_t*)W0, (const bf16_t*)W1, (const bf16_t*)W2, ldw, sW,
      C0, C1, C2, ldc, sC, (const bf16_t*)bias, res, scale, K);
}

extern "C" void kernel_launch(void* const* d_in, const int* in_sizes, int n_in,
                              void* d_out, int out_size, void* d_ws, size_t ws_size,
                              hipStream_t stream) {
  (void)in_sizes; (void)n_in; (void)out_size; (void)ws_size;
  const float* tgt  = (const float*)d_in[0];
  const float* mem  = (const float*)d_in[1];
  // d_in[2] (mask) unused: causality applied structurally.
  const float* sa_qw = (const float*)d_in[3];
  const float* sa_kw = (const float*)d_in[4];
  const float* sa_vw = (const float*)d_in[5];
  const float* sa_b  = (const float*)d_in[6];
  const float* sa_ow = (const float*)d_in[7];
  const float* sa_ob = (const float*)d_in[8];
  const float* ca_qw = (const float*)d_in[9];
  const float* ca_kw = (const float*)d_in[10];
  const float* ca_vw = (const float*)d_in[11];
  const float* ca_b  = (const float*)d_in[12];
  const float* ca_ow = (const float*)d_in[13];
  const float* ca_ob = (const float*)d_in[14];
  const float* ln1g = (const float*)d_in[15];
  const float* ln1b = (const float*)d_in[16];
  const float* ln2g = (const float*)d_in[17];
  const float* ln2b = (const float*)d_in[18];
  const float* ln3g = (const float*)d_in[19];
  const float* ln3b = (const float*)d_in[20];
  const float* w1 = (const float*)d_in[21];
  const float* b1 = (const float*)d_in[22];
  const float* w2 = (const float*)d_in[23];
  const float* b2 = (const float*)d_in[24];

  char* ws = (char*)d_ws;
  const size_t MB = 1048576;
  float*  xf   = (float*)(ws);             // [0,32)   fp32 residual
  bf16_t* hb   = (bf16_t*)(ws + 32 * MB);  // [32,48)  LN out
  bf16_t* vb   = (bf16_t*)(ws + 48 * MB);  // [48,64)  V
  bf16_t* qb   = (bf16_t*)(ws + 64 * MB);  // [64,80)  Q
  bf16_t* kb   = (bf16_t*)(ws + 80 * MB);  // [80,96)  K
  bf16_t* vt   = (bf16_t*)(ws + 96 * MB);  // [96,112) V^T [n][e][s]
  bf16_t* sb   = (bf16_t*)(ws + 32 * MB);  // [32,64)  scores/probs
  bf16_t* ao   = kb;                       // [80,96)  attn out (kb dead)
  bf16_t* hid  = (bf16_t*)(ws + 48 * MB);  // [48,112) MLP hidden
  bf16_t* memb = (bf16_t*)(ws + 112 * MB); // [112,128) bf16 memory
  bf16_t* wt   = (bf16_t*)(ws + 128 * MB); // [128,160) bf16 weights
  bf16_t* bb   = (bf16_t*)(ws + 160 * MB); // biases

  const size_t M1 = 1048576;  // elems per E*E weight
  bf16_t* saq = wt,          *sak = wt + M1,     *sav = wt + 2 * M1;
  bf16_t* sao = wt + 3 * M1, *caq = wt + 4 * M1, *cak = wt + 5 * M1;
  bf16_t* cav = wt + 6 * M1, *cao = wt + 7 * M1;
  bf16_t* w1b = wt + 8 * M1;   // 4M elems
  bf16_t* w2b = wt + 12 * M1;  // 4M elems

  const float qscale = 0.03125f;  // 1024^-0.5

  // ---- fused weight/bias conversions (one launch) ----
  CastDesc cd;
  auto seg = [&](int i, const float* s, bf16_t* d, int elems) {
    cd.s[i] = CastSeg{s, d, elems / 1024};
  };
  seg(0, sa_qw, saq, 1 << 20);  seg(1, sa_kw, sak, 1 << 20);
  seg(2, sa_vw, sav, 1 << 20);  seg(3, sa_ow, sao, 1 << 20);
  seg(4, ca_qw, caq, 1 << 20);  seg(5, ca_kw, cak, 1 << 20);
  seg(6, ca_vw, cav, 1 << 20);  seg(7, ca_ow, cao, 1 << 20);
  seg(8, w1, w1b, 1 << 22);     seg(9, w2, w2b, 1 << 22);
  seg(10, sa_b, bb, 3072);      seg(11, sa_ob, bb + 3072, 1024);
  seg(12, ca_b, bb + 4096, 3072); seg(13, ca_ob, bb + 7168, 1024);
  seg(14, b1, bb + 8192, 4096); seg(15, b2, bb + 12288, 1024);
  int total_chunks = 0;
  for (int i = 0; i < 16; ++i) total_chunks += cd.s[i].chunks;
  cast_multi<<<total_chunks, 256, 0, stream>>>(cd);
  f32_to_bf16_n<<<4096, 256, 0, stream>>>(mem, memb, 1 << 23);

  // ================= self-attention (causal) =================
  ln_kernel<<<8192, 256, 0, stream>>>(tgt, ln1g, ln1b, hb);
  launch_gemm<0, 3>(stream, 8192, 1024, 3, hb, hb, 1024, 0,
                    saq, sak, sav, 1024, 0, qb, kb, vb, 1024, 0,
                    bb, nullptr, qscale, 1024);
  transpose_v<<<dim3(32, 16, 4), 256, 0, stream>>>(vb, vt);
  launch_gemm<1, 1>(stream, 2048, 2048, 4, qb, nullptr, 4096, 1024,
                    kb, nullptr, nullptr, 4096, 1024,
                    sb, nullptr, nullptr, 2048, 4194304, nullptr, nullptr,
                    1.f, 1024);
  softmax_kernel<1><<<8192, 256, 0, stream>>>(sb);
  launch_gemm<0, 2>(stream, 2048, 1024, 4, sb, nullptr, 2048, 4194304,
                    vt, nullptr, nullptr, 2048, 2097152,
                    ao, nullptr, nullptr, 4096, 1024, nullptr, nullptr,
                    1.f, 2048);
  launch_gemm<2, 0>(stream, 8192, 1024, 1, ao, nullptr, 1024, 0,
                    sao, nullptr, nullptr, 1024, 0,
                    xf, nullptr, nullptr, 1024, 0, bb + 3072, tgt, 1.f, 1024);

  // ================= cross-attention (no mask) =================
  ln_kernel<<<8192, 256, 0, stream>>>(xf, ln2g, ln2b, hb);
  launch_gemm<0, 3>(stream, 8192, 1024, 3, hb, memb, 1024, 0,
                    caq, cak, cav, 1024, 0, qb, kb, vb, 1024, 0,
                    bb + 4096, nullptr, qscale, 1024);
  transpose_v<<<dim3(32, 16, 4), 256, 0, stream>>>(vb, vt);
  launch_gemm<1, 0>(stream, 2048, 2048, 4, qb, nullptr, 4096, 1024,
                    kb, nullptr, nullptr, 4096, 1024,
                    sb, nullptr, nullptr, 2048, 4194304, nullptr, nullptr,
                    1.f, 1024);
  softmax_kernel<0><<<8192, 256, 0, stream>>>(sb);
  launch_gemm<0, 0>(stream, 2048, 1024, 4, sb, nullptr, 2048, 4194304,
                    vt, nullptr, nullptr, 2048, 2097152,
                    ao, nullptr, nullptr, 4096, 1024, nullptr, nullptr,
                    1.f, 2048);
  launch_gemm<2, 0>(stream, 8192, 1024, 1, ao, nullptr, 1024, 0,
                    cao, nullptr, nullptr, 1024, 0,
                    xf, nullptr, nullptr, 1024, 0, bb + 7168, xf, 1.f, 1024);

  // ================= MLP (QuickGELU) =================
  ln_kernel<<<8192, 256, 0, stream>>>(xf, ln3g, ln3b, hb);
  launch_gemm<3, 0>(stream, 8192, 4096, 1, hb, nullptr, 1024, 0,
                    w1b, nullptr, nullptr, 1024, 0,
                    hid, nullptr, nullptr, 4096, 0, bb + 8192, nullptr,
                    1.f, 1024);
  launch_gemm<2, 0>(stream, 8192, 1024, 1, hid, nullptr, 4096, 0,
                    w2b, nullptr, nullptr, 4096, 0,
                    d_out, nullptr, nullptr, 1024, 0, bb + 12288, xf,
                    1.f, 4096);
}

// Round 7
// 857.599 us; speedup vs baseline: 1.3099x; 1.0490x over previous
//
#include <hip/hip_runtime.h>
#include <hip/hip_bf16.h>
#include <cstdint>
#include <cstddef>

// SingleheadTransformerDecoderLayer: L=S=2048, N=4, E=1024, FF=4096, fp32 I/O.
// Round 7: BK templated (NS = BK/32). NS=2 (BK=64, 64KB LDS dbuf) for the
// 512-block grids (proj x2, PV x2, MLP2) -- halves barrier-drain count; these
// grids are already capped at 2 blocks/CU so the LDS cost is free. NS=1 for
// QKV/score/MLP1 (>=1024 blocks keep TLP). LDS slab layout [ks][row][32]
// keeps the 64B row stride (same bank profile as BK=32).
//
// Workspace layout (161MB):
//   [0,32)    xf   : fp32 residual [8192,1024]
//   [32,48)   hb   : bf16 LN out
//   [48,64)   vb   : bf16 V          } sb bf16 scores [n][l][s] = [32,64)
//   [64,80)   qb   : bf16 Q          }   (hb,vb dead by score-GEMM time)
//   [80,96)   kb   : bf16 K  (reused as attn-out ao after score GEMM)
//   [96,112)  vt   : bf16 V^T [n][e][s]
//   [48,112)  hid  : bf16 MLP hidden [8192,4096] (vb,qb,kb,vt dead)
//   [112,128) memb : bf16 copy of `memory`
//   [128,160) wts  : bf16 weights; [160,161) bb : bf16 biases

using bf16_t = __bf16;
typedef __bf16 bf16x8 __attribute__((ext_vector_type(8)));
typedef __bf16 bf16x4 __attribute__((ext_vector_type(4)));
typedef float f32x4 __attribute__((ext_vector_type(4)));

// ---------------- async global->LDS, 16B/lane, wave-uniform LDS base --------
__device__ __forceinline__ void gll16(const void* g, void* lds) {
  __builtin_amdgcn_global_load_lds(
      (__attribute__((address_space(1))) void*)(g),
      (__attribute__((address_space(3))) void*)(lds), 16, 0, 0);
}

// ---------------- fp32 -> bf16 cast (8 elems/thread) ------------------------
__global__ __launch_bounds__(256) void f32_to_bf16_n(
    const float* __restrict__ in, bf16_t* __restrict__ out, int n) {
  const size_t i = ((size_t)blockIdx.x * 256 + threadIdx.x) * 8;
  if (i >= (size_t)n) return;
  f32x4 a = *(const f32x4*)(in + i);
  f32x4 b = *(const f32x4*)(in + i + 4);
  bf16x8 v;
#pragma unroll
  for (int j = 0; j < 4; ++j) { v[j] = (bf16_t)a[j]; v[4 + j] = (bf16_t)b[j]; }
  *(bf16x8*)(out + i) = v;
}

// ---------------- fused multi-segment fp32 -> bf16 cast ---------------------
struct CastSeg { const float* src; bf16_t* dst; int chunks; };
struct CastDesc { CastSeg s[16]; };
__global__ __launch_bounds__(256) void cast_multi(CastDesc d) {
  int blk = blockIdx.x, seg = 0, base = 0;
  while (blk - base >= d.s[seg].chunks) { base += d.s[seg].chunks; ++seg; }
  const size_t i = (size_t)(blk - base) * 1024 + threadIdx.x * 4;
  f32x4 a = *(const f32x4*)(d.s[seg].src + i);
  bf16x4 v;
#pragma unroll
  for (int j = 0; j < 4; ++j) v[j] = (bf16_t)a[j];
  *(bf16x4*)(d.s[seg].dst + i) = v;
}

// ---------------- LayerNorm over E=1024, one block per row ------------------
__global__ __launch_bounds__(256) void ln_kernel(
    const float* __restrict__ x, const float* __restrict__ g,
    const float* __restrict__ b, bf16_t* __restrict__ out) {
  const int row = blockIdx.x, tid = threadIdx.x;
  const float* xr = x + (size_t)row * 1024;
  float v0 = xr[tid], v1 = xr[tid + 256], v2 = xr[tid + 512], v3 = xr[tid + 768];
  float s = v0 + v1 + v2 + v3;
  float ss = v0 * v0 + v1 * v1 + v2 * v2 + v3 * v3;
#pragma unroll
  for (int off = 32; off > 0; off >>= 1) {
    s += __shfl_down(s, off, 64);
    ss += __shfl_down(ss, off, 64);
  }
  __shared__ float red[8];
  const int w = tid >> 6, lane = tid & 63;
  if (lane == 0) { red[w] = s; red[4 + w] = ss; }
  __syncthreads();
  s = red[0] + red[1] + red[2] + red[3];
  ss = red[4] + red[5] + red[6] + red[7];
  const float mean = s * (1.f / 1024.f);
  float var = ss * (1.f / 1024.f) - mean * mean;
  var = var < 0.f ? 0.f : var;
  const float inv = rsqrtf(var + 1e-5f);
  bf16_t* orow = out + (size_t)row * 1024;
  orow[tid]       = (bf16_t)((v0 - mean) * inv * g[tid]       + b[tid]);
  orow[tid + 256] = (bf16_t)((v1 - mean) * inv * g[tid + 256] + b[tid + 256]);
  orow[tid + 512] = (bf16_t)((v2 - mean) * inv * g[tid + 512] + b[tid + 512]);
  orow[tid + 768] = (bf16_t)((v3 - mean) * inv * g[tid + 768] + b[tid + 768]);
}

// ---------------- softmax over S=2048, bf16 in-place, optional causal -------
template <int CAUSAL>
__global__ __launch_bounds__(256) void softmax_kernel(bf16_t* __restrict__ sc) {
  const int row = blockIdx.x, tid = threadIdx.x;
  const int l = row & 2047;
  bf16_t* sr = sc + (size_t)row * 2048;
  float v[8];
  float mx = -3.4e38f;
#pragma unroll
  for (int i = 0; i < 8; ++i) {
    const int j = tid + i * 256;
    v[i] = (CAUSAL && j > l) ? -3.4e38f : (float)sr[j];
    mx = fmaxf(mx, v[i]);
  }
#pragma unroll
  for (int off = 32; off > 0; off >>= 1) mx = fmaxf(mx, __shfl_down(mx, off, 64));
  __shared__ float red[8];
  const int w = tid >> 6, lane = tid & 63;
  if (lane == 0) red[w] = mx;
  __syncthreads();
  mx = fmaxf(fmaxf(red[0], red[1]), fmaxf(red[2], red[3]));
  float sum = 0.f;
#pragma unroll
  for (int i = 0; i < 8; ++i) { v[i] = __expf(v[i] - mx); sum += v[i]; }
#pragma unroll
  for (int off = 32; off > 0; off >>= 1) sum += __shfl_down(sum, off, 64);
  if (lane == 0) red[4 + w] = sum;
  __syncthreads();
  sum = red[4] + red[5] + red[6] + red[7];
  const float r = 1.f / sum;
#pragma unroll
  for (int i = 0; i < 8; ++i) sr[tid + i * 256] = (bf16_t)(v[i] * r);
}

// ---------------- V transpose: [s*4+n, e] -> vt[n][e][s] --------------------
__global__ __launch_bounds__(256) void transpose_v(const bf16_t* __restrict__ v,
                                                   bf16_t* __restrict__ vt) {
  __shared__ bf16_t tile[64][72];
  const int n = blockIdx.z;
  const int s0 = blockIdx.x * 64, e0 = blockIdx.y * 64;
  const int tid = threadIdx.x;
#pragma unroll
  for (int j = 0; j < 2; ++j) {
    int flat = j * 256 + tid;
    int r = flat >> 3, c8 = (flat & 7) * 8;
    bf16x8 val = *(const bf16x8*)(v + ((size_t)(s0 + r) * 4 + n) * 1024 + e0 + c8);
#pragma unroll
    for (int i = 0; i < 8; ++i) tile[r][c8 + i] = val[i];
  }
  __syncthreads();
#pragma unroll
  for (int j = 0; j < 2; ++j) {
    int flat = j * 256 + tid;
    int er = flat >> 3, s8 = (flat & 7) * 8;
    bf16x8 val;
#pragma unroll
    for (int i = 0; i < 8; ++i) val[i] = tile[s8 + i][er];
    *(bf16x8*)(vt + ((size_t)n * 1024 + e0 + er) * 2048 + s0 + s8) = val;
  }
}

// ---------------- generic C = A @ W^T GEMM, double-buffered LDS -------------
// All operands bf16. 128x128 tile, BK = NS*32, 4 waves x (4x4) 16x16x32 MFMA,
// global_load_lds width-16 staging, one barrier per BK iter; prefetch of the
// next BK-tile issued after the barrier, in flight during MFMA.
// EPI: 0 = bf16 store (acc+bias)*scale; 1 = bf16 store acc;
//      2 = fp32 store res[idx]+acc+bias; 3 = QuickGELU -> bf16.
// MODE: 0 = plain (z = batch); 1 = causal score (skip col0 > row0);
//       2 = causal PV (K capped at row0+128); 3 = fused QKV.
template <int EPI, int MODE, int NS>
__global__ __launch_bounds__(256) void gemm_bt(
    const bf16_t* __restrict__ A, const bf16_t* __restrict__ Aalt,
    long lda, long sA,
    const bf16_t* __restrict__ W0, const bf16_t* __restrict__ W1,
    const bf16_t* __restrict__ W2, long ldw, long sW,
    void* __restrict__ C0, void* __restrict__ C1, void* __restrict__ C2,
    long ldc, long sC,
    const bf16_t* __restrict__ bias, const float* __restrict__ res,
    float scale, int K) {
  const size_t row0 = (size_t)blockIdx.y * 128;
  const size_t col0 = (size_t)blockIdx.x * 128;
  if (MODE == 1 && col0 > row0) return;  // fully-masked causal tile
  const int z = blockIdx.z;
  constexpr int BK = NS * 32;

  const bf16_t* Ap = (MODE == 3) ? (z == 0 ? A : Aalt) : A + (size_t)z * sA;
  const bf16_t* Wp = (MODE == 3) ? (z == 0 ? W0 : (z == 1 ? W1 : W2))
                                 : W0 + (size_t)z * sW;
  void* Cp = (MODE == 3) ? (z == 0 ? C0 : (z == 1 ? C1 : C2)) : C0;
  const size_t zoffC = (MODE == 3) ? 0 : (size_t)z * sC;
  const bf16_t* biasp = bias ? bias + (MODE == 3 ? z * 1024 : 0) : nullptr;
  const float scl = (MODE == 3 && z != 0) ? 1.f : scale;
  const int kend = (MODE == 2) ? min(K, (int)row0 + 128) : K;

  // [parity][kslice][row*32] -- 64B row stride within each slab
  __shared__ __align__(16) bf16_t As[2][NS][128 * 32];
  __shared__ __align__(16) bf16_t Bs[2][NS][128 * 32];
  const int tid = threadIdx.x;
  const int wv = tid >> 6, lane = tid & 63;
  const int quad = lane >> 4, l15 = lane & 15;
  const int wr = wv >> 1, wc = wv & 1;

  // staging: 512*NS chunks of 16B per operand; chunk c: ks=c>>9,
  // row=(c&511)>>2, col=ks*32+(c&3)*8; LDS elem offset = c*8 (contiguous).
  // Wave wv handles chunks wv*(128*NS) + j*64 + lane, j in [0, 2*NS).
  const bf16_t* gA[2 * NS];
  const bf16_t* gW[2 * NS];
  int lbase[2 * NS];  // wave-uniform LDS element base for (wv, j)
#pragma unroll
  for (int j = 0; j < 2 * NS; ++j) {
    const int c = wv * (128 * NS) + j * 64 + lane;
    const int ks = c >> 9;
    const int rr = (c & 511) >> 2;
    const int cc = ks * 32 + (c & 3) * 8;
    gA[j] = Ap + (row0 + rr) * lda + cc;
    gW[j] = Wp + (col0 + rr) * ldw + cc;
    lbase[j] = (wv * (128 * NS) + j * 64) * 8;
  }

  f32x4 acc[4][4];
#pragma unroll
  for (int mi = 0; mi < 4; ++mi)
#pragma unroll
    for (int ni = 0; ni < 4; ++ni) acc[mi][ni] = (f32x4)0.f;

  // prologue: stage k=0 into parity 0
#pragma unroll
  for (int j = 0; j < 2 * NS; ++j) {
    gll16(gA[j], &As[0][0][0] + lbase[j]);
    gll16(gW[j], &Bs[0][0][0] + lbase[j]);
  }

  int p = 0;
  for (int k0 = 0; k0 < kend; k0 += BK, p ^= 1) {
    __syncthreads();  // drains vmcnt(0): parity-p staging complete; also
                      // guarantees prior iter's ds_reads done before overwrite
    const int kn = k0 + BK;
    if (kn < kend) {  // prefetch parity p^1 -- in flight during MFMA below
#pragma unroll
      for (int j = 0; j < 2 * NS; ++j) {
        gll16(gA[j] + kn, &As[p ^ 1][0][0] + lbase[j]);
        gll16(gW[j] + kn, &Bs[p ^ 1][0][0] + lbase[j]);
      }
    }
#pragma unroll
    for (int ks = 0; ks < NS; ++ks) {
      bf16x8 af[4], bfv[4];
#pragma unroll
      for (int mi = 0; mi < 4; ++mi)
        af[mi] = *(const bf16x8*)(As[p][ks] + (wr * 64 + mi * 16 + l15) * 32 + quad * 8);
#pragma unroll
      for (int ni = 0; ni < 4; ++ni)
        bfv[ni] = *(const bf16x8*)(Bs[p][ks] + (wc * 64 + ni * 16 + l15) * 32 + quad * 8);
#pragma unroll
      for (int mi = 0; mi < 4; ++mi)
#pragma unroll
        for (int ni = 0; ni < 4; ++ni)
          acc[mi][ni] = __builtin_amdgcn_mfma_f32_16x16x32_bf16(
              af[mi], bfv[ni], acc[mi][ni], 0, 0, 0);
    }
  }

  // epilogue: C/D layout col=lane&15, row=quad*4+r (verified m89/m91)
  float* Cf = (float*)Cp;
  bf16_t* Cb = (bf16_t*)Cp;
#pragma unroll
  for (int mi = 0; mi < 4; ++mi) {
    const size_t gr = row0 + wr * 64 + mi * 16 + quad * 4;
#pragma unroll
    for (int ni = 0; ni < 4; ++ni) {
      const size_t gc = col0 + wc * 64 + ni * 16 + l15;
      float bv = 0.f;
      if (EPI == 0 || EPI == 2 || EPI == 3) bv = biasp ? (float)biasp[gc] : 0.f;
#pragma unroll
      for (int r = 0; r < 4; ++r) {
        float v = acc[mi][ni][r];
        const size_t idx = zoffC + (gr + r) * ldc + gc;
        if (EPI == 0) {
          Cb[idx] = (bf16_t)((v + bv) * scl);
        } else if (EPI == 1) {
          Cb[idx] = (bf16_t)v;
        } else if (EPI == 2) {
          Cf[idx] = res[idx] + v + bv;
        } else {
          float t = v + bv;
          Cb[idx] = (bf16_t)(t * (1.f / (1.f + __expf(-1.702f * t))));
        }
      }
    }
  }
}

// ---------------- host-side launch helper -----------------------------------
template <int EPI, int MODE, int NS = 1>
static void launch_gemm(hipStream_t stream, int M, int N, int Z,
                        const void* A, const void* Aalt, long lda, long sA,
                        const void* W0, const void* W1, const void* W2,
                        long ldw, long sW,
                        void* C0, void* C1, void* C2, long ldc, long sC,
                        const void* bias, const float* res, float scale, int K) {
  dim3 grid(N / 128, M / 128, Z);
  gemm_bt<EPI, MODE, NS><<<grid, dim3(256), 0, stream>>>(
      (const bf16_t*)A, (const bf16_t*)Aalt, lda, sA,
      (const bf16_t*)W0, (const bf16_t*)W1, (const bf16_t*)W2, ldw, sW,
      C0, C1, C2, ldc, sC, (const bf16_t*)bias, res, scale, K);
}

extern "C" void kernel_launch(void* const* d_in, const int* in_sizes, int n_in,
                              void* d_out, int out_size, void* d_ws, size_t ws_size,
                              hipStream_t stream) {
  (void)in_sizes; (void)n_in; (void)out_size; (void)ws_size;
  const float* tgt  = (const float*)d_in[0];
  const float* mem  = (const float*)d_in[1];
  // d_in[2] (mask) unused: causality applied structurally.
  const float* sa_qw = (const float*)d_in[3];
  const float* sa_kw = (const float*)d_in[4];
  const float* sa_vw = (const float*)d_in[5];
  const float* sa_b  = (const float*)d_in[6];
  const float* sa_ow = (const float*)d_in[7];
  const float* sa_ob = (const float*)d_in[8];
  const float* ca_qw = (const float*)d_in[9];
  const float* ca_kw = (const float*)d_in[10];
  const float* ca_vw = (const float*)d_in[11];
  const float* ca_b  = (const float*)d_in[12];
  const float* ca_ow = (const float*)d_in[13];
  const float* ca_ob = (const float*)d_in[14];
  const float* ln1g = (const float*)d_in[15];
  const float* ln1b = (const float*)d_in[16];
  const float* ln2g = (const float*)d_in[17];
  const float* ln2b = (const float*)d_in[18];
  const float* ln3g = (const float*)d_in[19];
  const float* ln3b = (const float*)d_in[20];
  const float* w1 = (const float*)d_in[21];
  const float* b1 = (const float*)d_in[22];
  const float* w2 = (const float*)d_in[23];
  const float* b2 = (const float*)d_in[24];

  char* ws = (char*)d_ws;
  const size_t MB = 1048576;
  float*  xf   = (float*)(ws);             // [0,32)   fp32 residual
  bf16_t* hb   = (bf16_t*)(ws + 32 * MB);  // [32,48)  LN out
  bf16_t* vb   = (bf16_t*)(ws + 48 * MB);  // [48,64)  V
  bf16_t* qb   = (bf16_t*)(ws + 64 * MB);  // [64,80)  Q
  bf16_t* kb   = (bf16_t*)(ws + 80 * MB);  // [80,96)  K
  bf16_t* vt   = (bf16_t*)(ws + 96 * MB);  // [96,112) V^T [n][e][s]
  bf16_t* sb   = (bf16_t*)(ws + 32 * MB);  // [32,64)  scores/probs
  bf16_t* ao   = kb;                       // [80,96)  attn out (kb dead)
  bf16_t* hid  = (bf16_t*)(ws + 48 * MB);  // [48,112) MLP hidden
  bf16_t* memb = (bf16_t*)(ws + 112 * MB); // [112,128) bf16 memory
  bf16_t* wt   = (bf16_t*)(ws + 128 * MB); // [128,160) bf16 weights
  bf16_t* bb   = (bf16_t*)(ws + 160 * MB); // biases

  const size_t M1 = 1048576;  // elems per E*E weight
  bf16_t* saq = wt,          *sak = wt + M1,     *sav = wt + 2 * M1;
  bf16_t* sao = wt + 3 * M1, *caq = wt + 4 * M1, *cak = wt + 5 * M1;
  bf16_t* cav = wt + 6 * M1, *cao = wt + 7 * M1;
  bf16_t* w1b = wt + 8 * M1;   // 4M elems
  bf16_t* w2b = wt + 12 * M1;  // 4M elems

  const float qscale = 0.03125f;  // 1024^-0.5

  // ---- fused weight/bias conversions (one launch) ----
  CastDesc cd;
  auto seg = [&](int i, const float* s, bf16_t* d, int elems) {
    cd.s[i] = CastSeg{s, d, elems / 1024};
  };
  seg(0, sa_qw, saq, 1 << 20);  seg(1, sa_kw, sak, 1 << 20);
  seg(2, sa_vw, sav, 1 << 20);  seg(3, sa_ow, sao, 1 << 20);
  seg(4, ca_qw, caq, 1 << 20);  seg(5, ca_kw, cak, 1 << 20);
  seg(6, ca_vw, cav, 1 << 20);  seg(7, ca_ow, cao, 1 << 20);
  seg(8, w1, w1b, 1 << 22);     seg(9, w2, w2b, 1 << 22);
  seg(10, sa_b, bb, 3072);      seg(11, sa_ob, bb + 3072, 1024);
  seg(12, ca_b, bb + 4096, 3072); seg(13, ca_ob, bb + 7168, 1024);
  seg(14, b1, bb + 8192, 4096); seg(15, b2, bb + 12288, 1024);
  int total_chunks = 0;
  for (int i = 0; i < 16; ++i) total_chunks += cd.s[i].chunks;
  cast_multi<<<total_chunks, 256, 0, stream>>>(cd);
  f32_to_bf16_n<<<4096, 256, 0, stream>>>(mem, memb, 1 << 23);

  // ================= self-attention (causal) =================
  ln_kernel<<<8192, 256, 0, stream>>>(tgt, ln1g, ln1b, hb);
  launch_gemm<0, 3>(stream, 8192, 1024, 3, hb, hb, 1024, 0,
                    saq, sak, sav, 1024, 0, qb, kb, vb, 1024, 0,
                    bb, nullptr, qscale, 1024);
  transpose_v<<<dim3(32, 16, 4), 256, 0, stream>>>(vb, vt);
  launch_gemm<1, 1>(stream, 2048, 2048, 4, qb, nullptr, 4096, 1024,
                    kb, nullptr, nullptr, 4096, 1024,
                    sb, nullptr, nullptr, 2048, 4194304, nullptr, nullptr,
                    1.f, 1024);
  softmax_kernel<1><<<8192, 256, 0, stream>>>(sb);
  launch_gemm<0, 2, 2>(stream, 2048, 1024, 4, sb, nullptr, 2048, 4194304,
                       vt, nullptr, nullptr, 2048, 2097152,
                       ao, nullptr, nullptr, 4096, 1024, nullptr, nullptr,
                       1.f, 2048);
  launch_gemm<2, 0, 2>(stream, 8192, 1024, 1, ao, nullptr, 1024, 0,
                       sao, nullptr, nullptr, 1024, 0,
                       xf, nullptr, nullptr, 1024, 0, bb + 3072, tgt,
                       1.f, 1024);

  // ================= cross-attention (no mask) =================
  ln_kernel<<<8192, 256, 0, stream>>>(xf, ln2g, ln2b, hb);
  launch_gemm<0, 3>(stream, 8192, 1024, 3, hb, memb, 1024, 0,
                    caq, cak, cav, 1024, 0, qb, kb, vb, 1024, 0,
                    bb + 4096, nullptr, qscale, 1024);
  transpose_v<<<dim3(32, 16, 4), 256, 0, stream>>>(vb, vt);
  launch_gemm<1, 0>(stream, 2048, 2048, 4, qb, nullptr, 4096, 1024,
                    kb, nullptr, nullptr, 4096, 1024,
                    sb, nullptr, nullptr, 2048, 4194304, nullptr, nullptr,
                    1.f, 1024);
  softmax_kernel<0><<<8192, 256, 0, stream>>>(sb);
  launch_gemm<0, 0, 2>(stream, 2048, 1024, 4, sb, nullptr, 2048, 4194304,
                       vt, nullptr, nullptr, 2048, 2097152,
                       ao, nullptr, nullptr, 4096, 1024, nullptr, nullptr,
                       1.f, 2048);
  launch_gemm<2, 0, 2>(stream, 8192, 1024, 1, ao, nullptr, 1024, 0,
                       cao, nullptr, nullptr, 1024, 0,
                       xf, nullptr, nullptr, 1024, 0, bb + 7168, xf,
                       1.f, 1024);

  // ================= MLP (QuickGELU) =================
  ln_kernel<<<8192, 256, 0, stream>>>(xf, ln3g, ln3b, hb);
  launch_gemm<3, 0>(stream, 8192, 4096, 1, hb, nullptr, 1024, 0,
                    w1b, nullptr, nullptr, 1024, 0,
                    hid, nullptr, nullptr, 4096, 0, bb + 8192, nullptr,
                    1.f, 1024);
  launch_gemm<2, 0, 2>(stream, 8192, 1024, 1, hid, nullptr, 4096, 0,
                       w2b, nullptr, nullptr, 4096, 0,
                       d_out, nullptr, nullptr, 1024, 0, bb + 12288, xf,
                       1.f, 4096);
}